// Round 7
// baseline (1708.584 us; speedup 1.0000x reference)
//
#include <hip/hip_runtime.h>
#include <stdint.h>

// ---------------------------------------------------------------------------
// Net_29137058136132: ImgEncoder (2048->512) + 6x Rs_GCN non-local blocks.
// B=256, N=100, C=512, DIMG=2048, L=6. fp32 in/out; bf16 MFMA, fp32 accum.
//
// Round-8 (resubmit; round-6 bench lost to GPUAcquisitionTimeout):
// k_rywp occupancy was grid-capped (256 blocks = 1 block/CU = 8 waves/CU;
// round-5 LDS shrink couldn't help). All work in the fused op is
// token-row-parallel -> split each batch into TWO half-token blocks
// (rows 0-49 / 50-99): grid 512 = 2 blocks/CU = 16 waves/CU, and per-block
// serial work halves. acc_W [7][4]->[4][4]; LDS 65.3 -> 34.8 KB;
// __launch_bounds__(512,4) pins 4 waves/SIMD (VGPR<=128).
// Old 5-dispatch path retained for ws < 93.3 MB.
// ---------------------------------------------------------------------------

typedef __bf16 bf16;
typedef float  f32x4  __attribute__((ext_vector_type(4)));
typedef bf16   bf16x4 __attribute__((ext_vector_type(4)));
typedef bf16   bf16x8 __attribute__((ext_vector_type(8)));

#define MTOT   25600   // 256*100 rows
#define CDIM   512
#define NTOK   100
#define NHALF  50      // tokens per k_rywp block
#define RPAD   128     // padded K for R
#define BN_EPS 1e-5f
#define NW_T   (2048 * 512)          // trans_w elems
#define NW_L   (6 * 512 * 512)       // per weight-tensor elems (all layers)

// async 16B/lane global->LDS. LDS dest must be wave-uniform base + lane*16.
__device__ __forceinline__ void gload16(const bf16* gsrc, bf16* lds_dst)
{
    __builtin_amdgcn_global_load_lds(
        (const __attribute__((address_space(1))) void*)gsrc,
        (__attribute__((address_space(3))) void*)lds_dst,
        16, 0, 0);
}

// ---------------- fp32 -> bf16 elementwise convert (n % 4 == 0) ------------
__global__ __launch_bounds__(256) void k_cvt(const float* __restrict__ s,
                                             bf16* __restrict__ d, int n)
{
    const int i = (blockIdx.x * 256 + threadIdx.x) * 4;
    if (i < n) {
        const f32x4 v = *(const f32x4*)(s + i);
        bf16x4 o;
#pragma unroll
        for (int e = 0; e < 4; ++e) o[e] = (bf16)v[e];
        *(bf16x4*)(d + i) = o;
    }
}

// all five weight tensors in one dispatch (z selects)
__global__ __launch_bounds__(256) void k_cvtw(const float* tw, const float* gw,
                                              const float* t2, const float* pw,
                                              const float* wwp,
                                              bf16* twd, bf16* gwd, bf16* t2d,
                                              bf16* pwd, bf16* wwd)
{
    const float* s; bf16* d; int n;
    switch (blockIdx.z) {
        case 0: s = tw;  d = twd; n = NW_T; break;
        case 1: s = gw;  d = gwd; n = NW_L; break;
        case 2: s = t2;  d = t2d; n = NW_L; break;
        case 3: s = pw;  d = pwd; n = NW_L; break;
        default: s = wwp; d = wwd; n = NW_L; break;
    }
    const int i = (blockIdx.x * 256 + threadIdx.x) * 4;
    if (i < n) {
        const f32x4 v = *(const f32x4*)(s + i);
        bf16x4 o;
#pragma unroll
        for (int e = 0; e < 4; ++e) o[e] = (bf16)v[e];
        *(bf16x4*)(d + i) = o;
    }
}

// ---------------------------------------------------------------------------
// 128x128-tile GEMM mainloop: C += A[m0:,:] * W[n0:,:]^T, BK=32, K%32==0.
// ---------------------------------------------------------------------------
template<bool ABF>
__device__ __forceinline__ void gemm_tile(const void* __restrict__ Av,
                                          const bf16* __restrict__ W,
                                          int K, int m0, int n0,
                                          bf16* As, bf16* Bs, f32x4 acc[4][4])
{
    const int tid  = threadIdx.x;
    const int lane = tid & 63, wave = tid >> 6;
    const int lrow = lane & 15, quad = lane >> 4;
    const int wm = (wave & 1) * 64, wn = (wave >> 1) * 64;
    const int r0 = tid >> 2;             // staging row 0..63 (+64 for u=1)
    const int kp = (tid & 3) * 8;        // staging k-offset (elements)

    const bf16* Wb0 = W + (size_t)(n0 + r0) * K + kp;
    const bf16* Wb1 = Wb0 + (size_t)64 * K;
    bf16* As0 = As + tid * 8;            // 16B per slot
    bf16* Bs0 = Bs + tid * 8;

    const bf16*  Ab0 = ABF ? (const bf16*)Av + (size_t)(m0 + r0) * K + kp : (const bf16*)nullptr;
    const bf16*  Ab1 = ABF ? Ab0 + (size_t)64 * K : (const bf16*)nullptr;
    const float* Af0 = ABF ? (const float*)nullptr : (const float*)Av + (size_t)(m0 + r0) * K + kp;
    const float* Af1 = ABF ? (const float*)nullptr : Af0 + (size_t)64 * K;

    for (int kt = 0; kt < K; kt += 32) {
        bf16x8 av0, av1;
        if (!ABF) {   // fp32 A: load+convert in regs (overlaps prev MFMAs)
            const f32x4 a0 = *(const f32x4*)(Af0 + kt);
            const f32x4 a1 = *(const f32x4*)(Af0 + kt + 4);
            const f32x4 a2 = *(const f32x4*)(Af1 + kt);
            const f32x4 a3 = *(const f32x4*)(Af1 + kt + 4);
#pragma unroll
            for (int e = 0; e < 4; ++e) {
                av0[e] = (bf16)a0[e]; av0[e + 4] = (bf16)a1[e];
                av1[e] = (bf16)a2[e]; av1[e + 4] = (bf16)a3[e];
            }
        }
        __syncthreads();                 // all waves done reading LDS
        if (ABF) {
            gload16(Ab0 + kt, As0);
            gload16(Ab1 + kt, As0 + 2048);
        } else {
            *(bf16x8*)As0          = av0;
            *(bf16x8*)(As0 + 2048) = av1;
        }
        gload16(Wb0 + kt, Bs0);
        gload16(Wb1 + kt, Bs0 + 2048);
        __syncthreads();                 // staging complete

        bf16x8 af[4], bv[4];
#pragma unroll
        for (int i = 0; i < 4; ++i)
            af[i] = *(const bf16x8*)(As + (wm + i * 16 + lrow) * 32 + quad * 8);
#pragma unroll
        for (int j = 0; j < 4; ++j)
            bv[j] = *(const bf16x8*)(Bs + (wn + j * 16 + lrow) * 32 + quad * 8);
#pragma unroll
        for (int i = 0; i < 4; ++i)
#pragma unroll
            for (int j = 0; j < 4; ++j)
                acc[i][j] = __builtin_amdgcn_mfma_f32_16x16x32_bf16(
                    af[i], bv[j], acc[i][j], 0, 0, 0);
    }
}

// ---------------- Encoder: xf = img @ trans_w^T + b; optional xb shadow ----
template<bool ABF>
__global__ __launch_bounds__(256) void k_enc(const void* __restrict__ img,
                                             const bf16* __restrict__ Wt,
                                             const float* __restrict__ bias,
                                             float* __restrict__ xf,
                                             bf16* __restrict__ xb)
{
    __shared__ __align__(16) bf16 As[128 * 32];
    __shared__ __align__(16) bf16 Bs[128 * 32];
    const int m0 = blockIdx.y * 128, n0 = blockIdx.x * 128;
    f32x4 acc[4][4] = {};
    gemm_tile<ABF>(img, Wt, 2048, m0, n0, As, Bs, acc);

    const int tid = threadIdx.x, wave = tid >> 6, lane = tid & 63;
    const int lrow = lane & 15, quad = lane >> 4;
    const int wm = (wave & 1) * 64, wn = (wave >> 1) * 64;
#pragma unroll
    for (int j = 0; j < 4; ++j) {
        const int col = n0 + wn + j * 16 + lrow;
        const float b = bias[col];
#pragma unroll
        for (int i = 0; i < 4; ++i) {
            const int row0 = m0 + wm + i * 16 + quad * 4;
#pragma unroll
            for (int r = 0; r < 4; ++r) {
                const size_t idx = (size_t)(row0 + r) * CDIM + col;
                const float v = acc[i][j][r] + b;
                xf[idx] = v;
                if (xb) xb[idx] = (bf16)v;
            }
        }
    }
}

// ---------------- 3 projections in one dispatch: z in {0,1,2} --------------
template<bool ABF>
__global__ __launch_bounds__(256) void k_proj3(const void* __restrict__ x,
                                               const bf16* __restrict__ W0, const float* __restrict__ b0,
                                               bf16* __restrict__ o0,
                                               const bf16* __restrict__ W1, const float* __restrict__ b1,
                                               bf16* __restrict__ o1,
                                               const bf16* __restrict__ W2, const float* __restrict__ b2,
                                               bf16* __restrict__ o2)
{
    __shared__ __align__(16) bf16 As[128 * 32];
    __shared__ __align__(16) bf16 Bs[128 * 32];
    const bf16*  W    = blockIdx.z == 0 ? W0 : (blockIdx.z == 1 ? W1 : W2);
    const float* bias = blockIdx.z == 0 ? b0 : (blockIdx.z == 1 ? b1 : b2);
    bf16*        out  = blockIdx.z == 0 ? o0 : (blockIdx.z == 1 ? o1 : o2);

    const int m0 = blockIdx.y * 128, n0 = blockIdx.x * 128;
    f32x4 acc[4][4] = {};
    gemm_tile<ABF>(x, W, 512, m0, n0, As, Bs, acc);

    const int tid = threadIdx.x, wave = tid >> 6, lane = tid & 63;
    const int lrow = lane & 15, quad = lane >> 4;
    const int wm = (wave & 1) * 64, wn = (wave >> 1) * 64;
#pragma unroll
    for (int j = 0; j < 4; ++j) {
        const int col = n0 + wn + j * 16 + lrow;
        const float b = bias[col];
#pragma unroll
        for (int i = 0; i < 4; ++i) {
            const int row0 = m0 + wm + i * 16 + quad * 4;
#pragma unroll
            for (int r = 0; r < 4; ++r)
                out[(size_t)(row0 + r) * CDIM + col] = (bf16)(acc[i][j][r] + b);
        }
    }
}

// ---------------- Projection(s), old path: z in {0,1} ----------------------
template<bool ABF>
__global__ __launch_bounds__(256) void k_proj2(const void* __restrict__ x,
                                               const bf16* __restrict__ W0, const float* __restrict__ b0,
                                               bf16* __restrict__ o0,
                                               const bf16* __restrict__ W1, const float* __restrict__ b1,
                                               bf16* __restrict__ o1)
{
    __shared__ __align__(16) bf16 As[128 * 32];
    __shared__ __align__(16) bf16 Bs[128 * 32];
    const bf16*  W    = blockIdx.z ? W1 : W0;
    const float* bias = blockIdx.z ? b1 : b0;
    bf16*        out  = blockIdx.z ? o1 : o0;

    const int m0 = blockIdx.y * 128, n0 = blockIdx.x * 128;
    f32x4 acc[4][4] = {};
    gemm_tile<ABF>(x, W, 512, m0, n0, As, Bs, acc);

    const int tid = threadIdx.x, wave = tid >> 6, lane = tid & 63;
    const int lrow = lane & 15, quad = lane >> 4;
    const int wm = (wave & 1) * 64, wn = (wave >> 1) * 64;
#pragma unroll
    for (int j = 0; j < 4; ++j) {
        const int col = n0 + wn + j * 16 + lrow;
        const float b = bias[col];
#pragma unroll
        for (int i = 0; i < 4; ++i) {
            const int row0 = m0 + wm + i * 16 + quad * 4;
#pragma unroll
            for (int r = 0; r < 4; ++r)
                out[(size_t)(row0 + r) * CDIM + col] = (bf16)(acc[i][j][r] + b);
        }
    }
}

// ---------------- W-proj + BN(eval) + residual (old path only) -------------
__global__ __launch_bounds__(256) void k_wproj(const bf16* __restrict__ Y,
                                               const bf16* __restrict__ Wt,
                                               const float* __restrict__ bias,
                                               const float* __restrict__ bng, const float* __restrict__ bnb,
                                               const float* __restrict__ bnm, const float* __restrict__ bnv,
                                               float* __restrict__ xf,
                                               bf16* __restrict__ xb)
{
    __shared__ __align__(16) bf16 As[128 * 32];
    __shared__ __align__(16) bf16 Bs[128 * 32];
    const int m0 = blockIdx.y * 128, n0 = blockIdx.x * 128;
    f32x4 acc[4][4] = {};
    gemm_tile<true>(Y, Wt, 512, m0, n0, As, Bs, acc);

    const int tid = threadIdx.x, wave = tid >> 6, lane = tid & 63;
    const int lrow = lane & 15, quad = lane >> 4;
    const int wm = (wave & 1) * 64, wn = (wave >> 1) * 64;
#pragma unroll
    for (int j = 0; j < 4; ++j) {
        const int col = n0 + wn + j * 16 + lrow;
        const float sc = bng[col] * rsqrtf(bnv[col] + BN_EPS);
        const float sh = (bias[col] - bnm[col]) * sc + bnb[col];
#pragma unroll
        for (int i = 0; i < 4; ++i) {
            const int row0 = m0 + wm + i * 16 + quad * 4;
#pragma unroll
            for (int r = 0; r < 4; ++r) {
                const size_t idx = (size_t)(row0 + r) * CDIM + col;
                const float v = xf[idx] + acc[i][j][r] * sc + sh;
                xf[idx] = v;
                if (xb) xb[idx] = (bf16)v;
            }
        }
    }
}

// ---------------------------------------------------------------------------
// Fused R + y + wproj + BN + residual. TWO blocks per batch (half tokens
// each: rows h*50..h*50+49), 512 thr (8 waves). grid 512 -> 2 blocks/CU.
// LDS = Rl(64x136) + Yc(64x136) = 34.8 KB. VGPR<=128 (launch_bounds(512,4)).
// Phase 1 (no barriers): R_half = th[half]@ph^T*0.01 -> Rl.
//   wave -> (row-tile wr=wave&3, col-half jh=wave>>2).
// Phase 2 (per 128-col chunk): y_half = R_half@g -> Yc; B-frag via 8 clamped
//   scalar global loads (m>=100 clamps to 99, multiplies Rl's zeroed pad
//   cols -> exact 0). 4 MFMAs per bv.
// Phase 3: acc_W[4][4] += Yc @ ww[:,chunk]^T (ww direct-from-global).
// Epilogue: BN + residual on this block's 50 token rows.
// ---------------------------------------------------------------------------
__global__ __launch_bounds__(512, 4) void k_rywp(const bf16* __restrict__ TH,
                                                 const bf16* __restrict__ PH,
                                                 const bf16* __restrict__ G,
                                                 const bf16* __restrict__ Wl,
                                                 const float* __restrict__ wbias,
                                                 const float* __restrict__ bng, const float* __restrict__ bnb,
                                                 const float* __restrict__ bnm, const float* __restrict__ bnv,
                                                 float* __restrict__ xf,
                                                 bf16* __restrict__ xb)
{
    __shared__ __align__(16) bf16 Rl[64 * 136];   // 17.4 KB  R half-tile
    __shared__ __align__(16) bf16 Yc[64 * 136];   // 17.4 KB  y half-chunk

    const int b  = blockIdx.x >> 1;
    const int n0 = (blockIdx.x & 1) * NHALF;      // token base: 0 or 50
    const bf16* th = TH + (size_t)b * NTOK * CDIM;
    const bf16* ph = PH + (size_t)b * NTOK * CDIM;
    const bf16* g  = G  + (size_t)b * NTOK * CDIM;

    const int tid = threadIdx.x, wave = tid >> 6, lane = tid & 63;
    const int lrow = lane & 15, quad = lane >> 4;

    // zero R half-tile (incl. pads): 4352 dwords
    uint32_t* rz = (uint32_t*)Rl;
#pragma unroll
    for (int i = 0; i < 9; ++i) {
        const int idx = tid + i * 512;
        if (idx < 64 * 136 / 2) rz[idx] = 0;
    }
    __syncthreads();

    // ---- phase 1: R_half = th[half] @ ph^T * 0.01 -> Rl (barrier-free) ----
    {
        const int wr = wave & 3, jh = wave >> 2;   // row-tile, col-half
        f32x4 accR[4] = {};
        int lr = wr * 16 + lrow; if (lr > NHALF - 1) lr = NHALF - 1;
        const bf16* thr = th + (size_t)(n0 + lr) * CDIM;
        for (int kt = 0; kt < CDIM; kt += 32) {
            const bf16x8 af = *(const bf16x8*)(thr + kt + quad * 8);
#pragma unroll
            for (int jj = 0; jj < 4; ++jj) {
                const int j = jh * 4 + jj;
                if (j < 7) {
                    int brow = j * 16 + lrow; if (brow > 99) brow = 99;
                    const bf16x8 bv = *(const bf16x8*)(ph + (size_t)brow * CDIM + kt + quad * 8);
                    accR[jj] = __builtin_amdgcn_mfma_f32_16x16x32_bf16(af, bv, accR[jj], 0, 0, 0);
                }
            }
        }
        const int row0 = wr * 16 + quad * 4;
#pragma unroll
        for (int jj = 0; jj < 4; ++jj) {
            const int j = jh * 4 + jj;
            if (j < 7) {
                const int col = j * 16 + lrow;
#pragma unroll
                for (int r = 0; r < 4; ++r) {
                    const int row = row0 + r;
                    if (row < NHALF && col < NTOK)
                        Rl[row * 136 + col] = (bf16)(accR[jj][r] * 0.01f);
                }
            }
        }
    }
    __syncthreads();

    // ---- phases 2+3: per 128-col chunk ------------------------------------
    f32x4 acc_W[4][4] = {};
    for (int cc0 = 0; cc0 < CDIM; cc0 += 128) {
        // (2a) y half-chunk = R_half @ g[:, cc0:cc0+128]
        const int ycol = cc0 + wave * 16 + lrow;   // this lane's y column
        f32x4 acc_y[4] = {};
#pragma unroll
        for (int kt = 0; kt < RPAD; kt += 32) {
            bf16x8 bv;
#pragma unroll
            for (int e = 0; e < 8; ++e) {
                int m = kt + quad * 8 + e; if (m > 99) m = 99;   // see header
                bv[e] = g[(size_t)m * CDIM + ycol];
            }
#pragma unroll
            for (int mt = 0; mt < 4; ++mt) {
                const bf16x8 af = *(const bf16x8*)(Rl + (mt * 16 + lrow) * 136 + kt + quad * 8);
                acc_y[mt] = __builtin_amdgcn_mfma_f32_16x16x32_bf16(af, bv, acc_y[mt], 0, 0, 0);
            }
        }
        __syncthreads();          // prev chunk's phase-3 Yc reads complete
        // (2b) -> Yc (bf16). rows >=50 are exact zeros (zeroed Rl rows).
#pragma unroll
        for (int mt = 0; mt < 4; ++mt) {
            const int r0 = mt * 16 + quad * 4;
#pragma unroll
            for (int r = 0; r < 4; ++r)
                Yc[(r0 + r) * 136 + wave * 16 + lrow] = (bf16)acc_y[mt][r];
        }
        __syncthreads();
        // (3) wproj partial: acc_W += Yc @ ww[:, cc0:cc0+128]^T
        for (int kt2 = 0; kt2 < 128; kt2 += 32) {
            bf16x8 af2[4], bv2[4];
#pragma unroll
            for (int mt = 0; mt < 4; ++mt)
                af2[mt] = *(const bf16x8*)(Yc + (mt * 16 + lrow) * 136 + kt2 + quad * 8);
#pragma unroll
            for (int j2 = 0; j2 < 4; ++j2)
                bv2[j2] = *(const bf16x8*)(Wl + (size_t)(wave * 64 + j2 * 16 + lrow) * CDIM
                                              + cc0 + kt2 + quad * 8);
#pragma unroll
            for (int mt = 0; mt < 4; ++mt)
#pragma unroll
                for (int j2 = 0; j2 < 4; ++j2)
                    acc_W[mt][j2] = __builtin_amdgcn_mfma_f32_16x16x32_bf16(
                        af2[mt], bv2[j2], acc_W[mt][j2], 0, 0, 0);
        }
    }

    // ---- epilogue: BN(eval) + residual on this block's 50 rows ------------
#pragma unroll
    for (int j2 = 0; j2 < 4; ++j2) {
        const int col = wave * 64 + j2 * 16 + lrow;
        const float sc = bng[col] * rsqrtf(bnv[col] + BN_EPS);
        const float sh = (wbias[col] - bnm[col]) * sc + bnb[col];
#pragma unroll
        for (int mt = 0; mt < 4; ++mt) {
            const int r0 = mt * 16 + quad * 4;
#pragma unroll
            for (int r = 0; r < 4; ++r) {
                const int row = r0 + r;
                if (row < NHALF) {
                    const size_t idx = ((size_t)b * NTOK + n0 + row) * CDIM + col;
                    const float v = xf[idx] + acc_W[mt][j2][r] * sc + sh;
                    xf[idx] = v;
                    if (xb) xb[idx] = (bf16)v;
                }
            }
        }
    }
}

// ---------------- old-path kernels (fallback, ws < NEW_MIN) ----------------
__global__ __launch_bounds__(256) void k_R(const bf16* __restrict__ TH,
                                           const bf16* __restrict__ PH,
                                           bf16* __restrict__ R)
{
    const int b = blockIdx.x;
    const bf16* th = TH + (size_t)b * NTOK * CDIM;
    const bf16* ph = PH + (size_t)b * NTOK * CDIM;
    bf16* Rb = R + (size_t)b * NTOK * RPAD;
    const int tid = threadIdx.x, wave = tid >> 6, lane = tid & 63;
    const int lrow = lane & 15, quad = lane >> 4;

    f32x4 acc[2][7] = {};
    for (int kt = 0; kt < CDIM; kt += 32) {
        bf16x8 af[2], bv[7];
#pragma unroll
        for (int i = 0; i < 2; ++i) {
            int row = (wave * 2 + i) * 16 + lrow; if (row > 99) row = 99;
            af[i] = *(const bf16x8*)(th + (size_t)row * CDIM + kt + quad * 8);
        }
#pragma unroll
        for (int j = 0; j < 7; ++j) {
            int row = j * 16 + lrow; if (row > 99) row = 99;
            bv[j] = *(const bf16x8*)(ph + (size_t)row * CDIM + kt + quad * 8);
        }
#pragma unroll
        for (int i = 0; i < 2; ++i)
#pragma unroll
            for (int j = 0; j < 7; ++j)
                acc[i][j] = __builtin_amdgcn_mfma_f32_16x16x32_bf16(
                    af[i], bv[j], acc[i][j], 0, 0, 0);
    }
#pragma unroll
    for (int i = 0; i < 2; ++i) {
        const int row0 = (wave * 2 + i) * 16 + quad * 4;
#pragma unroll
        for (int j = 0; j < 7; ++j) {
            const int col = j * 16 + lrow;
#pragma unroll
            for (int r = 0; r < 4; ++r) {
                const int row = row0 + r;
                if (row < NTOK && col < NTOK)
                    Rb[row * RPAD + col] = (bf16)(acc[i][j][r] * 0.01f);
            }
        }
    }
}

__global__ __launch_bounds__(256) void k_y(const bf16* __restrict__ R,
                                           const bf16* __restrict__ G,
                                           bf16* __restrict__ Y)
{
    const int b = blockIdx.y, cc0 = blockIdx.x * 128;
    const bf16* Rb = R + (size_t)b * NTOK * RPAD;
    const bf16* Gb = G + (size_t)b * NTOK * CDIM;
    bf16* Yb = Y + (size_t)b * NTOK * CDIM;
    __shared__ __align__(16) bf16 Bt[128 * 40];
    const int tid = threadIdx.x, wave = tid >> 6, lane = tid & 63;
    const int lrow = lane & 15, quad = lane >> 4;

    f32x4 acc[7][2] = {};
    for (int kt = 0; kt < RPAD; kt += 32) {
        __syncthreads();
#pragma unroll
        for (int i = 0; i < 2; ++i) {
            const int chunk = tid * 2 + i;
            const int kkk = chunk >> 4;
            const int cc8 = (chunk & 15) * 8;
            uint4 v; v.x = v.y = v.z = v.w = 0u;
            if (kt + kkk < NTOK)
                v = *(const uint4*)(Gb + (size_t)(kt + kkk) * CDIM + cc0 + cc8);
            const bf16* pv = (const bf16*)&v;
#pragma unroll
            for (int e = 0; e < 8; ++e) Bt[(cc8 + e) * 40 + kkk] = pv[e];
        }
        __syncthreads();
        bf16x8 af[7], bv[2];
#pragma unroll
        for (int mt = 0; mt < 7; ++mt) {
            int row = mt * 16 + lrow; if (row > 99) row = 99;
            af[mt] = *(const bf16x8*)(Rb + (size_t)row * RPAD + kt + quad * 8);
        }
#pragma unroll
        for (int jj = 0; jj < 2; ++jj)
            bv[jj] = *(const bf16x8*)(Bt + ((wave * 2 + jj) * 16 + lrow) * 40 + quad * 8);
#pragma unroll
        for (int mt = 0; mt < 7; ++mt)
#pragma unroll
            for (int jj = 0; jj < 2; ++jj)
                acc[mt][jj] = __builtin_amdgcn_mfma_f32_16x16x32_bf16(
                    af[mt], bv[jj], acc[mt][jj], 0, 0, 0);
    }
#pragma unroll
    for (int mt = 0; mt < 7; ++mt) {
        const int row0 = mt * 16 + quad * 4;
#pragma unroll
        for (int jj = 0; jj < 2; ++jj) {
            const int col = cc0 + (wave * 2 + jj) * 16 + lrow;
#pragma unroll
            for (int r = 0; r < 4; ++r) {
                const int row = row0 + r;
                if (row < NTOK) Yb[(size_t)row * CDIM + col] = (bf16)acc[mt][jj][r];
            }
        }
    }
}

// ---------------------------------------------------------------------------
extern "C" void kernel_launch(void* const* d_in, const int* in_sizes, int n_in,
                              void* d_out, int out_size, void* d_ws, size_t ws_size,
                              hipStream_t stream)
{
    const float* img     = (const float*)d_in[0];
    const float* trans_w = (const float*)d_in[1];
    const float* trans_b = (const float*)d_in[2];
    const float* gw = (const float*)d_in[3],  *gb = (const float*)d_in[4];
    const float* tw = (const float*)d_in[5],  *tb = (const float*)d_in[6];
    const float* pw = (const float*)d_in[7],  *pb = (const float*)d_in[8];
    const float* ww = (const float*)d_in[9],  *wb = (const float*)d_in[10];
    const float* bng = (const float*)d_in[11], *bnb = (const float*)d_in[12];
    const float* bnm = (const float*)d_in[13], *bnv = (const float*)d_in[14];

    float* xf = (float*)d_out;   // fp32 residual master == output

    // ws layout: weights | buf1 | buf2 | buf3 | [xb] | [imgb]
    char* ws = (char*)d_ws;
    bf16* twbf = (bf16*)ws;
    bf16* gwbf = twbf + NW_T;
    bf16* t2bf = gwbf + NW_L;
    bf16* pwbf = t2bf + NW_L;
    bf16* wwbf = pwbf + NW_L;
    bf16* buf1 = wwbf + NW_L;
    bf16* buf2 = buf1 + (size_t)MTOT * CDIM;
    bf16* buf3 = buf2 + (size_t)MTOT * CDIM;        // new: g; old path: R
    bf16* xb   = buf3 + (size_t)MTOT * CDIM;
    bf16* imgb = xb   + (size_t)MTOT * CDIM;

    const size_t NEW_MIN  = (size_t)((char*)xb - ws);                      //  93,323,264
    const size_t NEW_MID  = NEW_MIN + (size_t)MTOT * CDIM * sizeof(bf16);  // 119,537,664
    const size_t NEW_FULL = NEW_MID + (size_t)MTOT * 2048 * sizeof(bf16);  // 224,395,264

    const dim3 blk(256, 1, 1);
    k_cvtw<<<dim3(NW_L / 1024, 1, 5), blk, 0, stream>>>(trans_w, gw, tw, pw, ww,
                                                        twbf, gwbf, t2bf, pwbf, wwbf);

    if (ws_size >= NEW_MIN) {
        // ---------------- fused 2-dispatch-per-layer path ------------------
        const bool has_xb  = ws_size >= NEW_MID;
        const bool has_img = ws_size >= NEW_FULL;

        if (has_img) {
            k_cvt<<<dim3(MTOT * 2048 / 1024), blk, 0, stream>>>(img, imgb, MTOT * 2048);
            k_enc<true><<<dim3(4, 200, 1), blk, 0, stream>>>(imgb, twbf, trans_b, xf,
                                                             has_xb ? xb : nullptr);
        } else {
            k_enc<false><<<dim3(4, 200, 1), blk, 0, stream>>>(img, twbf, trans_b, xf,
                                                              has_xb ? xb : nullptr);
        }

        for (int l = 0; l < 6; ++l) {
            const size_t wo = (size_t)l * CDIM * CDIM, bo = (size_t)l * CDIM;
            // th -> buf1, ph -> buf2, g -> buf3 (g is R-independent)
            if (has_xb)
                k_proj3<true><<<dim3(4, 200, 3), blk, 0, stream>>>(xb,
                        t2bf + wo, tb + bo, buf1,
                        pwbf + wo, pb + bo, buf2,
                        gwbf + wo, gb + bo, buf3);
            else
                k_proj3<false><<<dim3(4, 200, 3), blk, 0, stream>>>(xf,
                        t2bf + wo, tb + bo, buf1,
                        pwbf + wo, pb + bo, buf2,
                        gwbf + wo, gb + bo, buf3);
            // R + y + wproj + BN + residual; 2 half-token blocks per batch
            bf16* xbn = (has_xb && l < 5) ? xb : nullptr;
            k_rywp<<<dim3(512, 1, 1), dim3(512, 1, 1), 0, stream>>>(
                    buf1, buf2, buf3, wwbf + wo, wb + bo,
                    bng + bo, bnb + bo, bnm + bo, bnv + bo, xf, xbn);
        }
    } else {
        // ---------------- old proven 5-dispatch MIN path -------------------
        bf16* R = buf3;
        const size_t R_B = (size_t)256 * NTOK * RPAD * 2;
        hipMemsetAsync(R, 0, R_B, stream);
        k_enc<false><<<dim3(4, 200, 1), blk, 0, stream>>>(img, twbf, trans_b, xf, nullptr);
        for (int l = 0; l < 6; ++l) {
            const size_t wo = (size_t)l * CDIM * CDIM, bo = (size_t)l * CDIM;
            k_proj2<false><<<dim3(4, 200, 2), blk, 0, stream>>>(xf, t2bf + wo, tb + bo, buf1,
                                                                pwbf + wo, pb + bo, buf2);
            k_R<<<dim3(256, 1, 1), blk, 0, stream>>>(buf1, buf2, R);
            k_proj2<false><<<dim3(4, 200, 1), blk, 0, stream>>>(xf, gwbf + wo, gb + bo, buf1,
                                                                gwbf + wo, gb + bo, buf1);
            k_y<<<dim3(4, 256, 1), blk, 0, stream>>>(R, buf1, buf2);
            k_wproj<<<dim3(4, 200, 1), blk, 0, stream>>>(buf2, wwbf + wo, wb + bo,
                                                         bng + bo, bnb + bo,
                                                         bnm + bo, bnv + bo, xf, nullptr);
        }
    }
}

// Round 8
// 1366.223 us; speedup vs baseline: 1.2506x; 1.2506x over previous
//
#include <hip/hip_runtime.h>
#include <stdint.h>

// ---------------------------------------------------------------------------
// Net_29137058136132: ImgEncoder (2048->512) + 6x Rs_GCN non-local blocks.
// B=256, N=100, C=512, DIMG=2048, L=6. fp32 in/out; bf16 MFMA, fp32 accum.
//
// Round-9: lessons r3/r5/r7: occupancy is NOT the lever (r7: 42% occ but 2x
// traffic -> slower); traffic + LDS conflicts + barrier count are. Back to
// 256 blocks (1/batch, no operand duplication), k_rywp data movement rebuilt:
//   - chunked panel staging: ph/g staged in 128-wide [112][.] panels with
//     coalesced row-major uint4 writes (no transpose-scatter). g transpose
//     moved to read side: 8x ds_read_u16 at row-stride 132 -> 2-way banks
//     (free, m136). The old 16-way Bt write conflict (1.1e7) is gone.
//   - stride discipline: b128 tiles (Rl/Phl/Yc) stride 136 (16B-aligned,
//     2-way); scalar-read tile (Gs) stride 132 (b64 writes, 2-way reads).
//   - ONE scratch region aliases Phl/Gs/Yc (disjoint live ranges):
//     LDS = 30.5 + 30.5 = 61 KB. Barriers ~72 -> ~27; 16-K-step MFMA runs
//     are barrier-free so the compiler can pipeline.
// Old 5-dispatch path retained for ws < 93.3 MB.
// ---------------------------------------------------------------------------

typedef __bf16 bf16;
typedef float  f32x4  __attribute__((ext_vector_type(4)));
typedef bf16   bf16x4 __attribute__((ext_vector_type(4)));
typedef bf16   bf16x8 __attribute__((ext_vector_type(8)));

#define MTOT   25600   // 256*100 rows
#define CDIM   512
#define NTOK   100
#define RPAD   128     // padded K for R
#define BN_EPS 1e-5f
#define NW_T   (2048 * 512)          // trans_w elems
#define NW_L   (6 * 512 * 512)       // per weight-tensor elems (all layers)

// async 16B/lane global->LDS. LDS dest must be wave-uniform base + lane*16.
__device__ __forceinline__ void gload16(const bf16* gsrc, bf16* lds_dst)
{
    __builtin_amdgcn_global_load_lds(
        (const __attribute__((address_space(1))) void*)gsrc,
        (__attribute__((address_space(3))) void*)lds_dst,
        16, 0, 0);
}

// ---------------- fp32 -> bf16 elementwise convert (n % 4 == 0) ------------
__global__ __launch_bounds__(256) void k_cvt(const float* __restrict__ s,
                                             bf16* __restrict__ d, int n)
{
    const int i = (blockIdx.x * 256 + threadIdx.x) * 4;
    if (i < n) {
        const f32x4 v = *(const f32x4*)(s + i);
        bf16x4 o;
#pragma unroll
        for (int e = 0; e < 4; ++e) o[e] = (bf16)v[e];
        *(bf16x4*)(d + i) = o;
    }
}

// all five weight tensors in one dispatch (z selects)
__global__ __launch_bounds__(256) void k_cvtw(const float* tw, const float* gw,
                                              const float* t2, const float* pw,
                                              const float* wwp,
                                              bf16* twd, bf16* gwd, bf16* t2d,
                                              bf16* pwd, bf16* wwd)
{
    const float* s; bf16* d; int n;
    switch (blockIdx.z) {
        case 0: s = tw;  d = twd; n = NW_T; break;
        case 1: s = gw;  d = gwd; n = NW_L; break;
        case 2: s = t2;  d = t2d; n = NW_L; break;
        case 3: s = pw;  d = pwd; n = NW_L; break;
        default: s = wwp; d = wwd; n = NW_L; break;
    }
    const int i = (blockIdx.x * 256 + threadIdx.x) * 4;
    if (i < n) {
        const f32x4 v = *(const f32x4*)(s + i);
        bf16x4 o;
#pragma unroll
        for (int e = 0; e < 4; ++e) o[e] = (bf16)v[e];
        *(bf16x4*)(d + i) = o;
    }
}

// ---------------------------------------------------------------------------
// 128x128-tile GEMM mainloop: C += A[m0:,:] * W[n0:,:]^T, BK=32, K%32==0.
// ---------------------------------------------------------------------------
template<bool ABF>
__device__ __forceinline__ void gemm_tile(const void* __restrict__ Av,
                                          const bf16* __restrict__ W,
                                          int K, int m0, int n0,
                                          bf16* As, bf16* Bs, f32x4 acc[4][4])
{
    const int tid  = threadIdx.x;
    const int lane = tid & 63, wave = tid >> 6;
    const int lrow = lane & 15, quad = lane >> 4;
    const int wm = (wave & 1) * 64, wn = (wave >> 1) * 64;
    const int r0 = tid >> 2;             // staging row 0..63 (+64 for u=1)
    const int kp = (tid & 3) * 8;        // staging k-offset (elements)

    const bf16* Wb0 = W + (size_t)(n0 + r0) * K + kp;
    const bf16* Wb1 = Wb0 + (size_t)64 * K;
    bf16* As0 = As + tid * 8;            // 16B per slot
    bf16* Bs0 = Bs + tid * 8;

    const bf16*  Ab0 = ABF ? (const bf16*)Av + (size_t)(m0 + r0) * K + kp : (const bf16*)nullptr;
    const bf16*  Ab1 = ABF ? Ab0 + (size_t)64 * K : (const bf16*)nullptr;
    const float* Af0 = ABF ? (const float*)nullptr : (const float*)Av + (size_t)(m0 + r0) * K + kp;
    const float* Af1 = ABF ? (const float*)nullptr : Af0 + (size_t)64 * K;

    for (int kt = 0; kt < K; kt += 32) {
        bf16x8 av0, av1;
        if (!ABF) {   // fp32 A: load+convert in regs (overlaps prev MFMAs)
            const f32x4 a0 = *(const f32x4*)(Af0 + kt);
            const f32x4 a1 = *(const f32x4*)(Af0 + kt + 4);
            const f32x4 a2 = *(const f32x4*)(Af1 + kt);
            const f32x4 a3 = *(const f32x4*)(Af1 + kt + 4);
#pragma unroll
            for (int e = 0; e < 4; ++e) {
                av0[e] = (bf16)a0[e]; av0[e + 4] = (bf16)a1[e];
                av1[e] = (bf16)a2[e]; av1[e + 4] = (bf16)a3[e];
            }
        }
        __syncthreads();                 // all waves done reading LDS
        if (ABF) {
            gload16(Ab0 + kt, As0);
            gload16(Ab1 + kt, As0 + 2048);
        } else {
            *(bf16x8*)As0          = av0;
            *(bf16x8*)(As0 + 2048) = av1;
        }
        gload16(Wb0 + kt, Bs0);
        gload16(Wb1 + kt, Bs0 + 2048);
        __syncthreads();                 // staging complete

        bf16x8 af[4], bv[4];
#pragma unroll
        for (int i = 0; i < 4; ++i)
            af[i] = *(const bf16x8*)(As + (wm + i * 16 + lrow) * 32 + quad * 8);
#pragma unroll
        for (int j = 0; j < 4; ++j)
            bv[j] = *(const bf16x8*)(Bs + (wn + j * 16 + lrow) * 32 + quad * 8);
#pragma unroll
        for (int i = 0; i < 4; ++i)
#pragma unroll
            for (int j = 0; j < 4; ++j)
                acc[i][j] = __builtin_amdgcn_mfma_f32_16x16x32_bf16(
                    af[i], bv[j], acc[i][j], 0, 0, 0);
    }
}

// ---------------- Encoder: xf = img @ trans_w^T + b; optional xb shadow ----
template<bool ABF>
__global__ __launch_bounds__(256) void k_enc(const void* __restrict__ img,
                                             const bf16* __restrict__ Wt,
                                             const float* __restrict__ bias,
                                             float* __restrict__ xf,
                                             bf16* __restrict__ xb)
{
    __shared__ __align__(16) bf16 As[128 * 32];
    __shared__ __align__(16) bf16 Bs[128 * 32];
    const int m0 = blockIdx.y * 128, n0 = blockIdx.x * 128;
    f32x4 acc[4][4] = {};
    gemm_tile<ABF>(img, Wt, 2048, m0, n0, As, Bs, acc);

    const int tid = threadIdx.x, wave = tid >> 6, lane = tid & 63;
    const int lrow = lane & 15, quad = lane >> 4;
    const int wm = (wave & 1) * 64, wn = (wave >> 1) * 64;
#pragma unroll
    for (int j = 0; j < 4; ++j) {
        const int col = n0 + wn + j * 16 + lrow;
        const float b = bias[col];
#pragma unroll
        for (int i = 0; i < 4; ++i) {
            const int row0 = m0 + wm + i * 16 + quad * 4;
#pragma unroll
            for (int r = 0; r < 4; ++r) {
                const size_t idx = (size_t)(row0 + r) * CDIM + col;
                const float v = acc[i][j][r] + b;
                xf[idx] = v;
                if (xb) xb[idx] = (bf16)v;
            }
        }
    }
}

// ---------------- 3 projections in one dispatch: z in {0,1,2} --------------
template<bool ABF>
__global__ __launch_bounds__(256) void k_proj3(const void* __restrict__ x,
                                               const bf16* __restrict__ W0, const float* __restrict__ b0,
                                               bf16* __restrict__ o0,
                                               const bf16* __restrict__ W1, const float* __restrict__ b1,
                                               bf16* __restrict__ o1,
                                               const bf16* __restrict__ W2, const float* __restrict__ b2,
                                               bf16* __restrict__ o2)
{
    __shared__ __align__(16) bf16 As[128 * 32];
    __shared__ __align__(16) bf16 Bs[128 * 32];
    const bf16*  W    = blockIdx.z == 0 ? W0 : (blockIdx.z == 1 ? W1 : W2);
    const float* bias = blockIdx.z == 0 ? b0 : (blockIdx.z == 1 ? b1 : b2);
    bf16*        out  = blockIdx.z == 0 ? o0 : (blockIdx.z == 1 ? o1 : o2);

    const int m0 = blockIdx.y * 128, n0 = blockIdx.x * 128;
    f32x4 acc[4][4] = {};
    gemm_tile<ABF>(x, W, 512, m0, n0, As, Bs, acc);

    const int tid = threadIdx.x, wave = tid >> 6, lane = tid & 63;
    const int lrow = lane & 15, quad = lane >> 4;
    const int wm = (wave & 1) * 64, wn = (wave >> 1) * 64;
#pragma unroll
    for (int j = 0; j < 4; ++j) {
        const int col = n0 + wn + j * 16 + lrow;
        const float b = bias[col];
#pragma unroll
        for (int i = 0; i < 4; ++i) {
            const int row0 = m0 + wm + i * 16 + quad * 4;
#pragma unroll
            for (int r = 0; r < 4; ++r)
                out[(size_t)(row0 + r) * CDIM + col] = (bf16)(acc[i][j][r] + b);
        }
    }
}

// ---------------- Projection(s), old path: z in {0,1} ----------------------
template<bool ABF>
__global__ __launch_bounds__(256) void k_proj2(const void* __restrict__ x,
                                               const bf16* __restrict__ W0, const float* __restrict__ b0,
                                               bf16* __restrict__ o0,
                                               const bf16* __restrict__ W1, const float* __restrict__ b1,
                                               bf16* __restrict__ o1)
{
    __shared__ __align__(16) bf16 As[128 * 32];
    __shared__ __align__(16) bf16 Bs[128 * 32];
    const bf16*  W    = blockIdx.z ? W1 : W0;
    const float* bias = blockIdx.z ? b1 : b0;
    bf16*        out  = blockIdx.z ? o1 : o0;

    const int m0 = blockIdx.y * 128, n0 = blockIdx.x * 128;
    f32x4 acc[4][4] = {};
    gemm_tile<ABF>(x, W, 512, m0, n0, As, Bs, acc);

    const int tid = threadIdx.x, wave = tid >> 6, lane = tid & 63;
    const int lrow = lane & 15, quad = lane >> 4;
    const int wm = (wave & 1) * 64, wn = (wave >> 1) * 64;
#pragma unroll
    for (int j = 0; j < 4; ++j) {
        const int col = n0 + wn + j * 16 + lrow;
        const float b = bias[col];
#pragma unroll
        for (int i = 0; i < 4; ++i) {
            const int row0 = m0 + wm + i * 16 + quad * 4;
#pragma unroll
            for (int r = 0; r < 4; ++r)
                out[(size_t)(row0 + r) * CDIM + col] = (bf16)(acc[i][j][r] + b);
        }
    }
}

// ---------------- W-proj + BN(eval) + residual (old path only) -------------
__global__ __launch_bounds__(256) void k_wproj(const bf16* __restrict__ Y,
                                               const bf16* __restrict__ Wt,
                                               const float* __restrict__ bias,
                                               const float* __restrict__ bng, const float* __restrict__ bnb,
                                               const float* __restrict__ bnm, const float* __restrict__ bnv,
                                               float* __restrict__ xf,
                                               bf16* __restrict__ xb)
{
    __shared__ __align__(16) bf16 As[128 * 32];
    __shared__ __align__(16) bf16 Bs[128 * 32];
    const int m0 = blockIdx.y * 128, n0 = blockIdx.x * 128;
    f32x4 acc[4][4] = {};
    gemm_tile<true>(Y, Wt, 512, m0, n0, As, Bs, acc);

    const int tid = threadIdx.x, wave = tid >> 6, lane = tid & 63;
    const int lrow = lane & 15, quad = lane >> 4;
    const int wm = (wave & 1) * 64, wn = (wave >> 1) * 64;
#pragma unroll
    for (int j = 0; j < 4; ++j) {
        const int col = n0 + wn + j * 16 + lrow;
        const float sc = bng[col] * rsqrtf(bnv[col] + BN_EPS);
        const float sh = (bias[col] - bnm[col]) * sc + bnb[col];
#pragma unroll
        for (int i = 0; i < 4; ++i) {
            const int row0 = m0 + wm + i * 16 + quad * 4;
#pragma unroll
            for (int r = 0; r < 4; ++r) {
                const size_t idx = (size_t)(row0 + r) * CDIM + col;
                const float v = xf[idx] + acc[i][j][r] * sc + sh;
                xf[idx] = v;
                if (xb) xb[idx] = (bf16)v;
            }
        }
    }
}

// ---------------------------------------------------------------------------
// Fused R + y + wproj + BN + residual, one block per batch, 512 thr (8 waves).
// LDS: Rl[112][136] (29.8 KB, b128 tiles) + Sc[112][136] scratch (29.8 KB)
// aliased across phases: Phl (P1, stride 136) / Gs (P2a, stride 132) /
// Yc (P2b-P3, stride 136). Total 59.5 KB.
// P1 per 128-K panel: coalesced-stage ph panel, 4 barrier-free K-steps.
// P2a per 128-chan chunk: coalesced-stage g panel [m][chan] (stride 132,
//   b64 writes); bv via 8 ds_read_u16 transposed reads (2-way banks, free);
//   m>=100 reads zeroed rows -> exact-0 contribution.
// P2b: y chunk -> Yc (C-layout scatter). P3: acc_W[7][4] += Yc @ ww^T.
// Barriers ~27 (was ~72). Epilogue: BN + residual.
// ---------------------------------------------------------------------------
__global__ __launch_bounds__(512) void k_rywp(const bf16* __restrict__ TH,
                                              const bf16* __restrict__ PH,
                                              const bf16* __restrict__ G,
                                              const bf16* __restrict__ Wl,
                                              const float* __restrict__ wbias,
                                              const float* __restrict__ bng, const float* __restrict__ bnb,
                                              const float* __restrict__ bnm, const float* __restrict__ bnv,
                                              float* __restrict__ xf,
                                              bf16* __restrict__ xb)
{
    __shared__ __align__(16) bf16 Rl[112 * 136];   // 29.8 KB R tile (stride 136)
    __shared__ __align__(16) bf16 Sc[112 * 136];   // 29.8 KB scratch (aliased)

    const int b = blockIdx.x;
    const bf16* th = TH + (size_t)b * NTOK * CDIM;
    const bf16* ph = PH + (size_t)b * NTOK * CDIM;
    const bf16* g  = G  + (size_t)b * NTOK * CDIM;

    const int tid = threadIdx.x, wave = tid >> 6, lane = tid & 63;
    const int lrow = lane & 15, quad = lane >> 4;

    // zero R tile (incl. row/col pads): 7616 dwords
    uint32_t* rz = (uint32_t*)Rl;
#pragma unroll
    for (int i = 0; i < 15; ++i) {
        const int idx = tid + i * 512;
        if (idx < 112 * 136 / 2) rz[idx] = 0;
    }
    __syncthreads();

    // staging slot (shared by P1/P2 stagers): 1792 slots of 8 bf16
    const int srow0 = tid >> 4;          // 0..31 (+32 per iter)
    const int sc8   = (tid & 15) * 8;    // 0..120

    // ---- phase 1: R = th @ ph^T * 0.01 -> Rl ------------------------------
    {
        f32x4 accR[7] = {};
        int arow = wave * 16 + lrow; if (arow > 99) arow = 99;
        const bf16* thr = th + (size_t)arow * CDIM;
        for (int c4 = 0; c4 < CDIM; c4 += 128) {
            // stage ph[:, c4:c4+128] -> Sc[112][136] (rows >=100 zeroed)
#pragma unroll
            for (int i = 0; i < 4; ++i) {
                const int row = srow0 + i * 32;           // 0..127
                if (row < 112) {
                    uint4 v; v.x = v.y = v.z = v.w = 0u;
                    if (row < NTOK)
                        v = *(const uint4*)(ph + (size_t)row * CDIM + c4 + sc8);
                    *(bf16x8*)(Sc + row * 136 + sc8) = *(const bf16x8*)&v;
                }
            }
            __syncthreads();
#pragma unroll
            for (int kk = 0; kk < 4; ++kk) {
                const int kt = c4 + kk * 32;
                const bf16x8 af = *(const bf16x8*)(thr + kt + quad * 8);
#pragma unroll
                for (int j = 0; j < 7; ++j) {
                    const bf16x8 bv = *(const bf16x8*)(Sc + (j * 16 + lrow) * 136
                                                          + kk * 32 + quad * 8);
                    accR[j] = __builtin_amdgcn_mfma_f32_16x16x32_bf16(af, bv, accR[j], 0, 0, 0);
                }
            }
            __syncthreads();   // panel reads done before next stage
        }
        const int row0 = wave * 16 + quad * 4;
#pragma unroll
        for (int j = 0; j < 7; ++j) {
            const int col = j * 16 + lrow;
#pragma unroll
            for (int r = 0; r < 4; ++r) {
                const int row = row0 + r;
                if (row < NTOK && col < NTOK)
                    Rl[row * 136 + col] = (bf16)(accR[j][r] * 0.01f);
            }
        }
    }
    __syncthreads();   // Rl complete

    // ---- phases 2+3: per 128-col chunk ------------------------------------
    f32x4 acc_W[7][4] = {};
    for (int cc0 = 0; cc0 < CDIM; cc0 += 128) {
        // stage g[:, cc0:cc0+128] -> Sc as Gs[112][132] (b64 writes; rows>=100 zero)
#pragma unroll
        for (int i = 0; i < 4; ++i) {
            const int row = srow0 + i * 32;
            if (row < 112) {
                uint4 v; v.x = v.y = v.z = v.w = 0u;
                if (row < NTOK)
                    v = *(const uint4*)(g + (size_t)row * CDIM + cc0 + sc8);
                uint2* p = (uint2*)(Sc + row * 132 + sc8);   // 8B-aligned
                p[0] = make_uint2(v.x, v.y);
                p[1] = make_uint2(v.z, v.w);
            }
        }
        __syncthreads();
        // (2a) y_chunk = R @ g[:, cc0:cc0+128]; bv via transposed LDS reads
        const int ycl = wave * 16 + lrow;            // local y column 0..127
        f32x4 acc_y[7] = {};
#pragma unroll
        for (int kt = 0; kt < RPAD; kt += 32) {
            bf16x8 bv;
#pragma unroll
            for (int e = 0; e < 8; ++e) {
                int m = kt + quad * 8 + e; if (m > 111) m = 111;  // zeroed rows
                bv[e] = Sc[m * 132 + ycl];
            }
#pragma unroll
            for (int mt = 0; mt < 7; ++mt) {
                const bf16x8 af = *(const bf16x8*)(Rl + (mt * 16 + lrow) * 136 + kt + quad * 8);
                acc_y[mt] = __builtin_amdgcn_mfma_f32_16x16x32_bf16(af, bv, acc_y[mt], 0, 0, 0);
            }
        }
        __syncthreads();   // all Gs reads done before Yc overwrites Sc
        // (2b) -> Yc (stride 136). rows 100..111 exact zeros (R pad rows).
#pragma unroll
        for (int mt = 0; mt < 7; ++mt) {
            const int r0 = mt * 16 + quad * 4;
#pragma unroll
            for (int r = 0; r < 4; ++r)
                Sc[(r0 + r) * 136 + ycl] = (bf16)acc_y[mt][r];
        }
        __syncthreads();
        // (3) wproj partial: acc_W += Yc @ ww[:, cc0:cc0+128]^T
        for (int kt2 = 0; kt2 < 128; kt2 += 32) {
            bf16x8 af2[7], bv2[4];
#pragma unroll
            for (int mt = 0; mt < 7; ++mt)
                af2[mt] = *(const bf16x8*)(Sc + (mt * 16 + lrow) * 136 + kt2 + quad * 8);
#pragma unroll
            for (int j2 = 0; j2 < 4; ++j2)
                bv2[j2] = *(const bf16x8*)(Wl + (size_t)(wave * 64 + j2 * 16 + lrow) * CDIM
                                              + cc0 + kt2 + quad * 8);
#pragma unroll
            for (int mt = 0; mt < 7; ++mt)
#pragma unroll
                for (int j2 = 0; j2 < 4; ++j2)
                    acc_W[mt][j2] = __builtin_amdgcn_mfma_f32_16x16x32_bf16(
                        af2[mt], bv2[j2], acc_W[mt][j2], 0, 0, 0);
        }
        __syncthreads();   // Yc reads done before next chunk's Gs staging
    }

    // ---- epilogue: BN(eval) + residual ------------------------------------
#pragma unroll
    for (int j2 = 0; j2 < 4; ++j2) {
        const int col = wave * 64 + j2 * 16 + lrow;
        const float sc = bng[col] * rsqrtf(bnv[col] + BN_EPS);
        const float sh = (wbias[col] - bnm[col]) * sc + bnb[col];
#pragma unroll
        for (int mt = 0; mt < 7; ++mt) {
            const int r0 = mt * 16 + quad * 4;
#pragma unroll
            for (int r = 0; r < 4; ++r) {
                const int row = r0 + r;
                if (row < NTOK) {
                    const size_t idx = ((size_t)b * NTOK + row) * CDIM + col;
                    const float v = xf[idx] + acc_W[mt][j2][r] * sc + sh;
                    xf[idx] = v;
                    if (xb) xb[idx] = (bf16)v;
                }
            }
        }
    }
}

// ---------------- old-path kernels (fallback, ws < NEW_MIN) ----------------
__global__ __launch_bounds__(256) void k_R(const bf16* __restrict__ TH,
                                           const bf16* __restrict__ PH,
                                           bf16* __restrict__ R)
{
    const int b = blockIdx.x;
    const bf16* th = TH + (size_t)b * NTOK * CDIM;
    const bf16* ph = PH + (size_t)b * NTOK * CDIM;
    bf16* Rb = R + (size_t)b * NTOK * RPAD;
    const int tid = threadIdx.x, wave = tid >> 6, lane = tid & 63;
    const int lrow = lane & 15, quad = lane >> 4;

    f32x4 acc[2][7] = {};
    for (int kt = 0; kt < CDIM; kt += 32) {
        bf16x8 af[2], bv[7];
#pragma unroll
        for (int i = 0; i < 2; ++i) {
            int row = (wave * 2 + i) * 16 + lrow; if (row > 99) row = 99;
            af[i] = *(const bf16x8*)(th + (size_t)row * CDIM + kt + quad * 8);
        }
#pragma unroll
        for (int j = 0; j < 7; ++j) {
            int row = j * 16 + lrow; if (row > 99) row = 99;
            bv[j] = *(const bf16x8*)(ph + (size_t)row * CDIM + kt + quad * 8);
        }
#pragma unroll
        for (int i = 0; i < 2; ++i)
#pragma unroll
            for (int j = 0; j < 7; ++j)
                acc[i][j] = __builtin_amdgcn_mfma_f32_16x16x32_bf16(
                    af[i], bv[j], acc[i][j], 0, 0, 0);
    }
#pragma unroll
    for (int i = 0; i < 2; ++i) {
        const int row0 = (wave * 2 + i) * 16 + quad * 4;
#pragma unroll
        for (int j = 0; j < 7; ++j) {
            const int col = j * 16 + lrow;
#pragma unroll
            for (int r = 0; r < 4; ++r) {
                const int row = row0 + r;
                if (row < NTOK && col < NTOK)
                    Rb[row * RPAD + col] = (bf16)(acc[i][j][r] * 0.01f);
            }
        }
    }
}

__global__ __launch_bounds__(256) void k_y(const bf16* __restrict__ R,
                                           const bf16* __restrict__ G,
                                           bf16* __restrict__ Y)
{
    const int b = blockIdx.y, cc0 = blockIdx.x * 128;
    const bf16* Rb = R + (size_t)b * NTOK * RPAD;
    const bf16* Gb = G + (size_t)b * NTOK * CDIM;
    bf16* Yb = Y + (size_t)b * NTOK * CDIM;
    __shared__ __align__(16) bf16 Bt[128 * 40];
    const int tid = threadIdx.x, wave = tid >> 6, lane = tid & 63;
    const int lrow = lane & 15, quad = lane >> 4;

    f32x4 acc[7][2] = {};
    for (int kt = 0; kt < RPAD; kt += 32) {
        __syncthreads();
#pragma unroll
        for (int i = 0; i < 2; ++i) {
            const int chunk = tid * 2 + i;
            const int kkk = chunk >> 4;
            const int cc8 = (chunk & 15) * 8;
            uint4 v; v.x = v.y = v.z = v.w = 0u;
            if (kt + kkk < NTOK)
                v = *(const uint4*)(Gb + (size_t)(kt + kkk) * CDIM + cc0 + cc8);
            const bf16* pv = (const bf16*)&v;
#pragma unroll
            for (int e = 0; e < 8; ++e) Bt[(cc8 + e) * 40 + kkk] = pv[e];
        }
        __syncthreads();
        bf16x8 af[7], bv[2];
#pragma unroll
        for (int mt = 0; mt < 7; ++mt) {
            int row = mt * 16 + lrow; if (row > 99) row = 99;
            af[mt] = *(const bf16x8*)(Rb + (size_t)row * RPAD + kt + quad * 8);
        }
#pragma unroll
        for (int jj = 0; jj < 2; ++jj)
            bv[jj] = *(const bf16x8*)(Bt + ((wave * 2 + jj) * 16 + lrow) * 40 + quad * 8);
#pragma unroll
        for (int mt = 0; mt < 7; ++mt)
#pragma unroll
            for (int jj = 0; jj < 2; ++jj)
                acc[mt][jj] = __builtin_amdgcn_mfma_f32_16x16x32_bf16(
                    af[mt], bv[jj], acc[mt][jj], 0, 0, 0);
    }
#pragma unroll
    for (int mt = 0; mt < 7; ++mt) {
        const int row0 = mt * 16 + quad * 4;
#pragma unroll
        for (int jj = 0; jj < 2; ++jj) {
            const int col = cc0 + (wave * 2 + jj) * 16 + lrow;
#pragma unroll
            for (int r = 0; r < 4; ++r) {
                const int row = row0 + r;
                if (row < NTOK) Yb[(size_t)row * CDIM + col] = (bf16)acc[mt][jj][r];
            }
        }
    }
}

// ---------------------------------------------------------------------------
extern "C" void kernel_launch(void* const* d_in, const int* in_sizes, int n_in,
                              void* d_out, int out_size, void* d_ws, size_t ws_size,
                              hipStream_t stream)
{
    const float* img     = (const float*)d_in[0];
    const float* trans_w = (const float*)d_in[1];
    const float* trans_b = (const float*)d_in[2];
    const float* gw = (const float*)d_in[3],  *gb = (const float*)d_in[4];
    const float* tw = (const float*)d_in[5],  *tb = (const float*)d_in[6];
    const float* pw = (const float*)d_in[7],  *pb = (const float*)d_in[8];
    const float* ww = (const float*)d_in[9],  *wb = (const float*)d_in[10];
    const float* bng = (const float*)d_in[11], *bnb = (const float*)d_in[12];
    const float* bnm = (const float*)d_in[13], *bnv = (const float*)d_in[14];

    float* xf = (float*)d_out;   // fp32 residual master == output

    // ws layout: weights | buf1 | buf2 | buf3 | [xb] | [imgb]
    char* ws = (char*)d_ws;
    bf16* twbf = (bf16*)ws;
    bf16* gwbf = twbf + NW_T;
    bf16* t2bf = gwbf + NW_L;
    bf16* pwbf = t2bf + NW_L;
    bf16* wwbf = pwbf + NW_L;
    bf16* buf1 = wwbf + NW_L;
    bf16* buf2 = buf1 + (size_t)MTOT * CDIM;
    bf16* buf3 = buf2 + (size_t)MTOT * CDIM;        // new: g; old path: R
    bf16* xb   = buf3 + (size_t)MTOT * CDIM;
    bf16* imgb = xb   + (size_t)MTOT * CDIM;

    const size_t NEW_MIN  = (size_t)((char*)xb - ws);                      //  93,323,264
    const size_t NEW_MID  = NEW_MIN + (size_t)MTOT * CDIM * sizeof(bf16);  // 119,537,664
    const size_t NEW_FULL = NEW_MID + (size_t)MTOT * 2048 * sizeof(bf16);  // 224,395,264

    const dim3 blk(256, 1, 1);
    k_cvtw<<<dim3(NW_L / 1024, 1, 5), blk, 0, stream>>>(trans_w, gw, tw, pw, ww,
                                                        twbf, gwbf, t2bf, pwbf, wwbf);

    if (ws_size >= NEW_MIN) {
        // ---------------- fused 2-dispatch-per-layer path ------------------
        const bool has_xb  = ws_size >= NEW_MID;
        const bool has_img = ws_size >= NEW_FULL;

        if (has_img) {
            k_cvt<<<dim3(MTOT * 2048 / 1024), blk, 0, stream>>>(img, imgb, MTOT * 2048);
            k_enc<true><<<dim3(4, 200, 1), blk, 0, stream>>>(imgb, twbf, trans_b, xf,
                                                             has_xb ? xb : nullptr);
        } else {
            k_enc<false><<<dim3(4, 200, 1), blk, 0, stream>>>(img, twbf, trans_b, xf,
                                                              has_xb ? xb : nullptr);
        }

        for (int l = 0; l < 6; ++l) {
            const size_t wo = (size_t)l * CDIM * CDIM, bo = (size_t)l * CDIM;
            // th -> buf1, ph -> buf2, g -> buf3 (g is R-independent)
            if (has_xb)
                k_proj3<true><<<dim3(4, 200, 3), blk, 0, stream>>>(xb,
                        t2bf + wo, tb + bo, buf1,
                        pwbf + wo, pb + bo, buf2,
                        gwbf + wo, gb + bo, buf3);
            else
                k_proj3<false><<<dim3(4, 200, 3), blk, 0, stream>>>(xf,
                        t2bf + wo, tb + bo, buf1,
                        pwbf + wo, pb + bo, buf2,
                        gwbf + wo, gb + bo, buf3);
            // R + y + wproj + BN + residual in one kernel; Y stays in LDS
            bf16* xbn = (has_xb && l < 5) ? xb : nullptr;
            k_rywp<<<dim3(256, 1, 1), dim3(512, 1, 1), 0, stream>>>(
                    buf1, buf2, buf3, wwbf + wo, wb + bo,
                    bng + bo, bnb + bo, bnm + bo, bnv + bo, xf, xbn);
        }
    } else {
        // ---------------- old proven 5-dispatch MIN path -------------------
        bf16* R = buf3;
        const size_t R_B = (size_t)256 * NTOK * RPAD * 2;
        hipMemsetAsync(R, 0, R_B, stream);
        k_enc<false><<<dim3(4, 200, 1), blk, 0, stream>>>(img, twbf, trans_b, xf, nullptr);
        for (int l = 0; l < 6; ++l) {
            const size_t wo = (size_t)l * CDIM * CDIM, bo = (size_t)l * CDIM;
            k_proj2<false><<<dim3(4, 200, 2), blk, 0, stream>>>(xf, t2bf + wo, tb + bo, buf1,
                                                                pwbf + wo, pb + bo, buf2);
            k_R<<<dim3(256, 1, 1), blk, 0, stream>>>(buf1, buf2, R);
            k_proj2<false><<<dim3(4, 200, 1), blk, 0, stream>>>(xf, gwbf + wo, gb + bo, buf1,
                                                                gwbf + wo, gb + bo, buf1);
            k_y<<<dim3(4, 256, 1), blk, 0, stream>>>(R, buf1, buf2);
            k_wproj<<<dim3(4, 200, 1), blk, 0, stream>>>(buf2, wwbf + wo, wb + bo,
                                                         bng + bo, bnb + bo,
                                                         bnm + bo, bnv + bo, xf, nullptr);
        }
    }
}